// Round 6
// baseline (285.660 us; speedup 1.0000x reference)
//
#include <hip/hip_runtime.h>
#include <hip/hip_bf16.h>

#define D 128
#define CHUNK 8192   // edges per build block

// NOTE: build path packs (dst&255, src) into one uint -> requires N <= 65536.

typedef __attribute__((ext_vector_type(8))) short short8;
typedef __attribute__((ext_vector_type(4))) float floatx4;

// fp32 -> bf16 round-to-nearest-even (bit pattern)
static __device__ inline unsigned int f2bf(float f) {
    unsigned int u = __float_as_uint(f);
    return (u + 0x7FFFu + ((u >> 16) & 1u)) >> 16;
}
static __device__ inline float4 bf4_to_f4(uint2 p) {
    float4 v;
    v.x = __uint_as_float(p.x << 16);
    v.y = __uint_as_float(p.x & 0xFFFF0000u);
    v.z = __uint_as_float(p.y << 16);
    v.w = __uint_as_float(p.y & 0xFFFF0000u);
    return v;
}

// ---------------------------------------------------------------- K0: swizzle W0/W1 into MFMA B-fragment order, hi/lo bf16 split
__global__ __launch_bounds__(256) void k0_swizzle(const float* __restrict__ W0,
                                                  const float* __restrict__ W1,
                                                  short8* __restrict__ whi0, short8* __restrict__ wlo0,
                                                  short8* __restrict__ whi1, short8* __restrict__ wlo1) {
    int gid = blockIdx.x * 256 + threadIdx.x; // 0..4095
    const float* W = (gid < 2048) ? W0 : W1;
    short8* whi = (gid < 2048) ? whi0 : whi1;
    short8* wlo = (gid < 2048) ? wlo0 : wlo1;
    int tid = gid & 2047;
    int t = tid >> 8, q = (tid >> 6) & 3, lane = tid & 63;
    short8 hi, lo;
    #pragma unroll
    for (int j = 0; j < 8; ++j) {
        int k = q * 32 + (lane >> 4) * 8 + j;
        int n = t * 16 + (lane & 15);
        float w = W[k * D + n];
        unsigned int h = f2bf(w);
        hi[j] = (short)h;
        lo[j] = (short)f2bf(w - __uint_as_float(h << 16));
    }
    whi[tid] = hi;
    wlo[tid] = lo;
}

// ---------------------------------------------------------------- K1: per-chunk bucket histogram (LDS only)
__global__ __launch_bounds__(256) void k1_hist(const int* __restrict__ dst,
                                               int* __restrict__ blockhist, int E_) {
    __shared__ int h[256];
    const int b = blockIdx.x, tid = threadIdx.x;
    h[tid] = 0;
    __syncthreads();
    const int e0 = b * CHUNK;
    const int e1 = min(E_, e0 + CHUNK);
    for (int e = e0 + tid; e < e1; e += 256)
        atomicAdd(&h[dst[e] >> 8], 1);
    __syncthreads();
    blockhist[b * 256 + tid] = h[tid];
}

// ---------------------------------------------------------------- K2: redundant full-table scan per block
__global__ __launch_bounds__(256) void k2_scan(const int* __restrict__ blockhist,
                                               int* __restrict__ gbase,
                                               int* __restrict__ bucket_offs,
                                               int NB, int NBUK, int E_) {
    __shared__ int s[256];
    const int myb = blockIdx.x, tid = threadIdx.x;
    int total = 0, prefix = 0;
    #pragma unroll 4
    for (int b2 = 0; b2 < NB; ++b2) {
        int t = blockhist[b2 * 256 + tid];
        total += t;
        prefix += (b2 < myb) ? t : 0;
    }
    s[tid] = total;
    __syncthreads();
    #pragma unroll
    for (int off = 1; off < 256; off <<= 1) {
        int x = (tid >= off) ? s[tid - off] : 0;
        __syncthreads();
        s[tid] += x;
        __syncthreads();
    }
    int bstart = s[tid] - total; // exclusive
    gbase[myb * 256 + tid] = bstart + prefix;
    if (myb == 0) {
        if (tid < NBUK) bucket_offs[tid] = bstart;
        if (tid == 0) bucket_offs[NBUK] = E_;
    }
}

// ---------------------------------------------------------------- K3: scatter packed (vlow,src) into bucket-major staging
__global__ __launch_bounds__(256) void k3_scatter(const int* __restrict__ dst,
                                                  const int* __restrict__ src,
                                                  const int* __restrict__ gbase,
                                                  unsigned int* __restrict__ buf, int E_) {
    __shared__ int c[256];
    const int b = blockIdx.x, tid = threadIdx.x;
    c[tid] = gbase[b * 256 + tid];
    __syncthreads();
    const int e0 = b * CHUNK;
    const int e1 = min(E_, e0 + CHUNK);
    for (int e = e0 + tid; e < e1; e += 256) {
        int v = dst[e];
        int sdx = src[e];
        int pos = atomicAdd(&c[v >> 8], 1);
        buf[pos] = (unsigned int)sdx | ((unsigned int)(v & 255) << 16);
    }
}

// ---------------------------------------------------------------- K4: per-bucket counting sort by (dst&255, src>>11)
// Emits col lists sorted by coarse src tile -> co-resident aggregate blocks
// sweep src ascending in lock-step => instantaneous gather working set fits L2.
__global__ __launch_bounds__(256) void k4_bucket(const unsigned int* __restrict__ buf,
                                                 const int* __restrict__ bucket_offs,
                                                 int* __restrict__ offs,
                                                 float* __restrict__ dinv,
                                                 int* __restrict__ col, int N_, int E_) {
    __shared__ int h[8192]; // 256 nodes x 32 src-tiles; reused as cursor after scan
    __shared__ int s[256];
    const int beta = blockIdx.x, tid = threadIdx.x;
    const int start = bucket_offs[beta];
    const int end   = bucket_offs[beta + 1];

    #pragma unroll
    for (int j = tid; j < 8192; j += 256) h[j] = 0;
    __syncthreads();
    for (int e = start + tid; e < end; e += 256) {
        unsigned int p = buf[e];
        int key = (int)((p >> 16) & 255) * 32 + (int)((p & 0xFFFFu) >> 11);
        atomicAdd(&h[key], 1);
    }
    __syncthreads();

    // node tid owns bins [tid*32, tid*32+32)
    const int base = tid * 32;
    int loc[32];
    int deg = 0;
    #pragma unroll
    for (int j = 0; j < 32; ++j) { loc[j] = h[base + j]; deg += loc[j]; }

    s[tid] = deg;
    __syncthreads();
    #pragma unroll
    for (int off = 1; off < 256; off <<= 1) {
        int x = (tid >= off) ? s[tid - off] : 0;
        __syncthreads();
        s[tid] += x;
        __syncthreads();
    }
    int excl = s[tid] - deg;

    // write exclusive bin cursors (global positions)
    int run = start + excl;
    #pragma unroll
    for (int j = 0; j < 32; ++j) { int t = loc[j]; h[base + j] = run; run += t; }

    int v0 = beta * 256 + tid;
    if (v0 < N_) {
        offs[v0] = start + excl;
        dinv[v0] = rsqrtf((float)(deg + 1));
    }
    if (beta == 0 && tid == 0) offs[N_] = E_;
    __syncthreads();

    for (int e = start + tid; e < end; e += 256) {
        unsigned int p = buf[e];
        int key = (int)((p >> 16) & 255) * 32 + (int)((p & 0xFFFFu) >> 11);
        int pos = atomicAdd(&h[key], 1);
        col[pos] = (int)(p & 0xFFFFu);
    }
}

// ---------------------------------------------------------------- MFMA GEMM: Gb(bf16) = (A @ W) * dinv[row]
__global__ __launch_bounds__(256) void gemm_mfma(const float* __restrict__ A,
                                                 const short8* __restrict__ whi,
                                                 const short8* __restrict__ wlo,
                                                 const float* __restrict__ dinv,
                                                 uint2* __restrict__ Gb, int nrows) {
    __shared__ float tileT[128][65];

    const int tid  = threadIdx.x;
    const int wave = tid >> 6, lane = tid & 63;
    const int m = lane & 15, quad = lane >> 4;
    const int rowInBlk = wave * 16;
    const int arow = min(blockIdx.x * 64 + rowInBlk + m, nrows - 1);
    const float* Ap = A + (size_t)arow * D + quad * 8;

    floatx4 acc[8];
    #pragma unroll
    for (int t = 0; t < 8; ++t) acc[t] = (floatx4){0.f, 0.f, 0.f, 0.f};

    #pragma unroll
    for (int q = 0; q < 4; ++q) {
        float4 a0 = *(const float4*)(Ap + q * 32);
        float4 a1 = *(const float4*)(Ap + q * 32 + 4);
        float av[8] = {a0.x, a0.y, a0.z, a0.w, a1.x, a1.y, a1.z, a1.w};
        short8 ahi, alo;
        #pragma unroll
        for (int j = 0; j < 8; ++j) {
            unsigned int h = f2bf(av[j]);
            ahi[j] = (short)h;
            alo[j] = (short)f2bf(av[j] - __uint_as_float(h << 16));
        }
        #pragma unroll
        for (int t = 0; t < 8; ++t) {
            short8 bh = whi[(t * 4 + q) * 64 + lane];
            short8 bl = wlo[(t * 4 + q) * 64 + lane];
            acc[t] = __builtin_amdgcn_mfma_f32_16x16x32_bf16(ahi, bh, acc[t], 0, 0, 0);
            acc[t] = __builtin_amdgcn_mfma_f32_16x16x32_bf16(alo, bh, acc[t], 0, 0, 0);
            acc[t] = __builtin_amdgcn_mfma_f32_16x16x32_bf16(ahi, bl, acc[t], 0, 0, 0);
        }
    }

    #pragma unroll
    for (int t = 0; t < 8; ++t)
        #pragma unroll
        for (int r = 0; r < 4; ++r)
            tileT[t * 16 + m][rowInBlk + quad * 4 + r] = acc[t][r];
    __syncthreads();

    const int orow = tid >> 2, seg = tid & 3;
    const int grow = blockIdx.x * 64 + orow;
    if (grow < nrows) {
        float s = dinv[grow];
        #pragma unroll
        for (int i = 0; i < 4; ++i) {
            int c = seg * 32 + i * 8;
            float v0 = tileT[c + 0][orow] * s, v1 = tileT[c + 1][orow] * s;
            float v2 = tileT[c + 2][orow] * s, v3 = tileT[c + 3][orow] * s;
            float v4 = tileT[c + 4][orow] * s, v5 = tileT[c + 5][orow] * s;
            float v6 = tileT[c + 6][orow] * s, v7 = tileT[c + 7][orow] * s;
            uint4 o4;
            o4.x = f2bf(v0) | (f2bf(v1) << 16);
            o4.y = f2bf(v2) | (f2bf(v3) << 16);
            o4.z = f2bf(v4) | (f2bf(v5) << 16);
            o4.w = f2bf(v6) | (f2bf(v7) << 16);
            *(uint4*)&Gb[(size_t)grow * 32 + seg * 8 + i * 2] = o4;
        }
    }
}

// ---------------------------------------------------------------- out[i] = relu(dinv[i]*(sum_j g[j] + g[i]) + b)
__global__ __launch_bounds__(256) void aggregate_kernel(const uint2* __restrict__ Gb,
                                                        const int* __restrict__ offs,
                                                        const int* __restrict__ col,
                                                        const float* __restrict__ dinv,
                                                        const float* __restrict__ bias,
                                                        float* __restrict__ out, int nnodes) {
    const int lane = threadIdx.x & 31;
    const int node = blockIdx.x * 8 + (threadIdx.x >> 5);
    if (node >= nnodes) return;

    float4 acc = bf4_to_f4(Gb[(size_t)node * 32 + lane]); // self-loop
    int s = offs[node];
    int e = offs[node + 1];

    int idx = s;
    for (; idx + 16 <= e; idx += 16) {
        int j[16];
        #pragma unroll
        for (int u = 0; u < 16; ++u) j[u] = col[idx + u];
        uint2 p[16];
        #pragma unroll
        for (int u = 0; u < 16; ++u) p[u] = Gb[(size_t)j[u] * 32 + lane];
        float4 t0 = make_float4(0.f, 0.f, 0.f, 0.f);
        float4 t1 = make_float4(0.f, 0.f, 0.f, 0.f);
        #pragma unroll
        for (int u = 0; u < 16; u += 2) {
            float4 v0 = bf4_to_f4(p[u]);
            float4 v1 = bf4_to_f4(p[u + 1]);
            t0.x += v0.x; t0.y += v0.y; t0.z += v0.z; t0.w += v0.w;
            t1.x += v1.x; t1.y += v1.y; t1.z += v1.z; t1.w += v1.w;
        }
        acc.x += t0.x + t1.x; acc.y += t0.y + t1.y;
        acc.z += t0.z + t1.z; acc.w += t0.w + t1.w;
    }
    for (; idx + 4 <= e; idx += 4) {
        int j0 = col[idx + 0], j1 = col[idx + 1], j2 = col[idx + 2], j3 = col[idx + 3];
        float4 v0 = bf4_to_f4(Gb[(size_t)j0 * 32 + lane]);
        float4 v1 = bf4_to_f4(Gb[(size_t)j1 * 32 + lane]);
        float4 v2 = bf4_to_f4(Gb[(size_t)j2 * 32 + lane]);
        float4 v3 = bf4_to_f4(Gb[(size_t)j3 * 32 + lane]);
        acc.x += (v0.x + v1.x) + (v2.x + v3.x);
        acc.y += (v0.y + v1.y) + (v2.y + v3.y);
        acc.z += (v0.z + v1.z) + (v2.z + v3.z);
        acc.w += (v0.w + v1.w) + (v2.w + v3.w);
    }
    for (; idx < e; ++idx) {
        float4 v = bf4_to_f4(Gb[(size_t)col[idx] * 32 + lane]);
        acc.x += v.x; acc.y += v.y; acc.z += v.z; acc.w += v.w;
    }

    float dv = dinv[node];
    float4 b = *(const float4*)&bias[lane * 4];
    float4 o;
    o.x = fmaxf(fmaf(dv, acc.x, b.x), 0.f);
    o.y = fmaxf(fmaf(dv, acc.y, b.y), 0.f);
    o.z = fmaxf(fmaf(dv, acc.z, b.z), 0.f);
    o.w = fmaxf(fmaf(dv, acc.w, b.w), 0.f);
    *(float4*)&out[node * D + lane * 4] = o;
}

// ----------------------------------------------------------------
extern "C" void kernel_launch(void* const* d_in, const int* in_sizes, int n_in,
                              void* d_out, int out_size, void* d_ws, size_t ws_size,
                              hipStream_t stream) {
    const float* x    = (const float*)d_in[0];
    const int*   edge = (const int*)d_in[1];
    const float* W0   = (const float*)d_in[2];
    const float* b0   = (const float*)d_in[3];
    const float* W1   = (const float*)d_in[4];
    const float* b1   = (const float*)d_in[5];
    float* out = (float*)d_out;

    const int N_ = in_sizes[0] / D;
    const int E_ = in_sizes[1] / 2;
    const int* srcp = edge;       // edge_index[0]
    const int* dstp = edge + E_;  // edge_index[1]

    const int NB   = (E_ + CHUNK - 1) / CHUNK;
    const int NBUK = (N_ + 255) >> 8;

    char* p = (char*)d_ws;
    auto carve = [&](size_t bytes) { char* q = p; p += (bytes + 255) & ~(size_t)255; return q; };
    int*          blockhist = (int*)          carve((size_t)NB * 256 * 4);
    int*          gbase     = (int*)          carve((size_t)NB * 256 * 4);
    int*          buck_offs = (int*)          carve((size_t)(NBUK + 1) * 4);
    int*          offs      = (int*)          carve((size_t)(N_ + 1) * 4);
    float*        dinv      = (float*)        carve((size_t)N_ * 4);
    unsigned int* buf       = (unsigned int*) carve((size_t)E_ * 4);
    int*          col       = (int*)          carve((size_t)E_ * 4);
    uint2*        gb        = (uint2*)        carve((size_t)N_ * D * 2);
    short8*       whi0      = (short8*)       carve(2048 * 16);
    short8*       wlo0      = (short8*)       carve(2048 * 16);
    short8*       whi1      = (short8*)       carve(2048 * 16);
    short8*       wlo1      = (short8*)       carve(2048 * 16);

    k0_swizzle<<<16,   256, 0, stream>>>(W0, W1, whi0, wlo0, whi1, wlo1);
    k1_hist   <<<NB,   256, 0, stream>>>(dstp, blockhist, E_);
    k2_scan   <<<NB,   256, 0, stream>>>(blockhist, gbase, buck_offs, NB, NBUK, E_);
    k3_scatter<<<NB,   256, 0, stream>>>(dstp, srcp, gbase, buf, E_);
    k4_bucket <<<NBUK, 256, 0, stream>>>(buf, buck_offs, offs, dinv, col, N_, E_);

    const int gmb = (N_ + 63) / 64;
    const int ab  = (N_ + 7) / 8;

    gemm_mfma       <<<gmb, 256, 0, stream>>>(x, whi0, wlo0, dinv, gb, N_);
    aggregate_kernel<<<ab,  256, 0, stream>>>(gb, offs, col, dinv, b0, out, N_);
    gemm_mfma       <<<gmb, 256, 0, stream>>>(out, whi1, wlo1, dinv, gb, N_);
    aggregate_kernel<<<ab,  256, 0, stream>>>(gb, offs, col, dinv, b1, out, N_);
}